// Round 4
// baseline (204.171 us; speedup 1.0000x reference)
//
#include <hip/hip_runtime.h>
#include <hip/hip_cooperative_groups.h>

namespace cg = cooperative_groups;

#define G_     8
#define D_     144
#define O_     32
#define CIN_   16
#define BATCH_ 8
#define KDIM_  (D_*G_)            // 1152
#define NPIX_  (BATCH_*64*64)     // 32768
#define KC_    (KDIM_/32)         // 36
#define NBLK_  512

typedef float  f32x4   __attribute__((ext_vector_type(4)));
typedef short  short8v __attribute__((ext_vector_type(8)));

// ws layout:
//   [0, 73728)         Bpack: ushort[36][2][64][8]  bf16 B-fragments
//   [73728, 204800)    part:  float[512][64]  (s[32] | q[32]) per block
#define PART_OFF  73728

__device__ __forceinline__ unsigned int pack2bf(float a, float b) {
    unsigned int ua = __float_as_uint(a) + 0x8000u;
    unsigned int ub = __float_as_uint(b) + 0x8000u;
    return __builtin_amdgcn_perm(ub, ua, 0x07060302u);   // {hi16(ub),hi16(ua)}
}

__global__ void __launch_bounds__(256, 2)
fused_kernel(const float* __restrict__ x, const float* __restrict__ W,
             const float* __restrict__ gamma, const float* __restrict__ beta,
             float* __restrict__ out, unsigned short* __restrict__ Bpack,
             float* __restrict__ part) {
    constexpr float A_S = 2.1019642153762871f;   // sqrt(log2 e) * 7/4

    __shared__ uint4 Bsh[KC_ * 2 * 64];          // 73728 B; reused in phase 2b/3
    cg::grid_group grid = cg::this_grid();

    const int tid = threadIdx.x;
    const int bid = blockIdx.x;
    const int gt  = bid * 256 + tid;

    // ---------- phase 0: issue this block's x loads (hide under phase 1) ----------
    const int l  = tid & 63;
    const int wv = tid >> 6;
    const int m  = l & 15;        // output channel base / D-col
    const int hi = l >> 4;        // k-group
    const int pixbase = bid * 64 + wv * 16;
    const int n  = pixbase + m;
    const int b  = n >> 12;
    const int y  = (n >> 6) & 63;
    const int xc = n & 63;
    const float* xb = x + ((size_t)b << 16);

    float p[KC_];
#pragma unroll
    for (int kc = 0; kc < KC_; ++kc) {
        int d  = kc * 4 + hi;
        int c  = (d * 57) >> 9;          // d/9
        int r9 = d - c * 9;
        int kh = (r9 * 11) >> 5;         // r9/3
        int kw = r9 - kh * 3;
        int iy = y + kh - 1;
        int ix = xc + kw - 1;
        bool valid = ((unsigned)iy < 64u) & ((unsigned)ix < 64u);
        p[kc] = valid ? xb[(c << 12) + (iy << 6) + ix] : 0.f;
    }

    // ---------- phase 1: Wsum -> bf16 B-fragments (288 blocks busy) ----------
    if (gt < 2 * O_ * KDIM_) {           // 73728 threads, 2 per (o,k)
        int pr = gt >> 1;
        int h  = gt & 1;
        int o  = pr / KDIM_;
        int k  = pr - o * KDIM_;
        const float* wp = W + (size_t)o * (D_ * KDIM_) + (size_t)(h * 72) * KDIM_ + k;
        float s = 0.f;
#pragma unroll 9
        for (int dd = 0; dd < 72; ++dd) s += wp[(size_t)dd * KDIM_];
        s += __shfl_xor(s, 1);           // partner holds other 72 d's
        if (h == 0) {
            unsigned int u = __float_as_uint(s);
            u += 0x7FFFu + ((u >> 16) & 1u);          // RNE to bf16
            unsigned short hb = (unsigned short)(u >> 16);
            int kc = k >> 5, lane_ = (((k >> 3) & 3) << 4) | (o & 15);
            int hh = o >> 4, e = k & 7;
            Bpack[(((kc * 2 + hh) * 64) + lane_) * 8 + e] = hb;
        }
    }
    __threadfence();
    grid.sync();

    // ---------- phase 2: stage B, basis + MFMA ----------
    const uint4* Bg = reinterpret_cast<const uint4*>(Bpack);
#pragma unroll
    for (int i = 0; i < 18; ++i) {
        int idx = tid + i * 256;
        Bsh[idx] = Bg[idx];
    }
    __syncthreads();

    f32x4 acc0 = {0.f, 0.f, 0.f, 0.f};
    f32x4 acc1 = {0.f, 0.f, 0.f, 0.f};

#pragma unroll
    for (int kc = 0; kc < KC_; ++kc) {
        float pv = p[kc];
        float e[G_];
#pragma unroll
        for (int g = 0; g < G_; ++g) {
            float gv = -2.0f + (float)g * (4.0f / 7.0f);
            float r  = fmaf(pv, A_S, -gv * A_S);
            e[g] = __builtin_amdgcn_exp2f(-(r * r));
        }
        uint4 au;
        au.x = pack2bf(e[0], e[1]);
        au.y = pack2bf(e[2], e[3]);
        au.z = pack2bf(e[4], e[5]);
        au.w = pack2bf(e[6], e[7]);
        short8v afrag = __builtin_bit_cast(short8v, au);

        short8v b0 = __builtin_bit_cast(short8v, Bsh[(kc * 2 + 0) * 64 + l]);
        short8v b1 = __builtin_bit_cast(short8v, Bsh[(kc * 2 + 1) * 64 + l]);
        acc0 = __builtin_amdgcn_mfma_f32_16x16x32_bf16(afrag, b0, acc0, 0, 0, 0);
        acc1 = __builtin_amdgcn_mfma_f32_16x16x32_bf16(afrag, b1, acc1, 0, 0, 0);
    }

    // ---------- phase 2b: per-block BN partials from registers ----------
    float s0 = acc0.x + acc0.y + acc0.z + acc0.w;
    float q0 = acc0.x*acc0.x + acc0.y*acc0.y + acc0.z*acc0.z + acc0.w*acc0.w;
    float s1 = acc1.x + acc1.y + acc1.z + acc1.w;
    float q1 = acc1.x*acc1.x + acc1.y*acc1.y + acc1.z*acc1.z + acc1.w*acc1.w;
    s0 += __shfl_xor(s0, 16); s0 += __shfl_xor(s0, 32);
    q0 += __shfl_xor(q0, 16); q0 += __shfl_xor(q0, 32);
    s1 += __shfl_xor(s1, 16); s1 += __shfl_xor(s1, 32);
    q1 += __shfl_xor(q1, 16); q1 += __shfl_xor(q1, 32);

    float* red = (float*)Bsh;            // Bsh no longer needed
    __syncthreads();
    if (l < 16) {                        // lanes 0-15 hold group sums
        red[wv * 64 +       m] = s0;     // s, ch m
        red[wv * 64 + 16 +  m] = s1;     // s, ch m+16
        red[wv * 64 + 32 +  m] = q0;     // q, ch m
        red[wv * 64 + 48 +  m] = q1;     // q, ch m+16
    }
    __syncthreads();
    if (tid < 64) {
        float v = red[tid] + red[64 + tid] + red[128 + tid] + red[192 + tid];
        part[bid * 64 + tid] = v;        // [0..31]=s per ch, [32..63]=q per ch
    }
    __threadfence();
    grid.sync();

    // ---------- phase 3: global stat reduce + BN apply + store ----------
    {
        int ch  = tid & 63;
        int seg = tid >> 6;
        float a = 0.f;
#pragma unroll 8
        for (int i = 0; i < 128; ++i)
            a += part[(seg * 128 + i) * 64 + ch];
        red[tid] = a;                    // red[seg*64+ch]
    }
    __syncthreads();
    if (tid < 64) {
        float tot = red[tid] + red[64 + tid] + red[128 + tid] + red[192 + tid];
        red[256 + tid] = tot;
    }
    if (tid < 32) {                      // same wave as writer: program order ok
        float S = red[256 + tid];
        float Q = red[256 + 32 + tid];
        float mean = S * (1.f / (float)NPIX_);
        float var  = Q * (1.f / (float)NPIX_) - mean * mean;
        float rstd = rsqrtf(var + 1e-5f);
        float sc   = gamma[tid] * rstd;
        red[320 + tid] = sc;
        red[352 + tid] = beta[tid] - mean * sc;
    }
    __syncthreads();

    float sc0 = red[320 + m],      sh0 = red[352 + m];
    float sc1 = red[320 + 16 + m], sh1 = red[352 + 16 + m];
    acc0.x = acc0.x * sc0 + sh0; acc0.y = acc0.y * sc0 + sh0;
    acc0.z = acc0.z * sc0 + sh0; acc0.w = acc0.w * sc0 + sh0;
    acc1.x = acc1.x * sc1 + sh1; acc1.y = acc1.y * sc1 + sh1;
    acc1.z = acc1.z * sc1 + sh1; acc1.w = acc1.w * sc1 + sh1;

    int prp = (pixbase & 4095) + hi * 4;
    float* dst0 = out + (((size_t)(b * O_ + m)) << 12) + prp;
    float* dst1 = out + (((size_t)(b * O_ + m + 16)) << 12) + prp;
    *reinterpret_cast<f32x4*>(dst0) = acc0;
    *reinterpret_cast<f32x4*>(dst1) = acc1;
}

extern "C" void kernel_launch(void* const* d_in, const int* in_sizes, int n_in,
                              void* d_out, int out_size, void* d_ws, size_t ws_size,
                              hipStream_t stream) {
    const float* x     = (const float*)d_in[0];
    const float* W     = (const float*)d_in[1];
    const float* gamma = (const float*)d_in[2];
    const float* beta  = (const float*)d_in[3];
    float* out = (float*)d_out;
    unsigned short* Bpack = (unsigned short*)d_ws;
    float* part = (float*)((char*)d_ws + PART_OFF);

    void* args[] = {(void*)&x, (void*)&W, (void*)&gamma, (void*)&beta,
                    (void*)&out, (void*)&Bpack, (void*)&part};
    hipLaunchCooperativeKernel((const void*)fused_kernel, dim3(NBLK_), dim3(256),
                               args, 0, stream);
}

// Round 5
// 29.784 us; speedup vs baseline: 6.8552x; 6.8552x over previous
//
#include <hip/hip_runtime.h>

#define G_     8
#define D_     144
#define O_     32
#define CIN_   16
#define BATCH_ 8
#define KDIM_  (D_*G_)            // 1152
#define NPIX_  (BATCH_*64*64)     // 32768
#define KC_    (KDIM_/32)         // 36
#define NBLK_  512

typedef float  f32x4   __attribute__((ext_vector_type(4)));
typedef short  short8v __attribute__((ext_vector_type(8)));

// ws layout:
//   [0, 73728)         Bpack: ushort[36][2][64][8]  bf16 B-fragments
//   [73728, 204800)    part:  float[512][64]  (s[32] | q[32]) per main-block
#define PART_OFF  73728

__device__ __forceinline__ unsigned int pack2bf(float a, float b) {
    unsigned int ua = __float_as_uint(a) + 0x8000u;
    unsigned int ub = __float_as_uint(b) + 0x8000u;
    return __builtin_amdgcn_perm(ub, ua, 0x07060302u);   // {hi16(ub),hi16(ua)}
}

// ---------- Wsum -> bf16 B-fragments; 4 threads per (o,k) ----------
__global__ void __launch_bounds__(256)
wsum_kernel(const float* __restrict__ W, unsigned short* __restrict__ Bpack) {
    int t  = blockIdx.x * 256 + threadIdx.x;     // 147456 threads
    int pr = t >> 2, q = t & 3;
    int o  = pr / KDIM_;
    int k  = pr - o * KDIM_;
    const float* p = W + (size_t)o * (D_ * KDIM_) + (size_t)(q * 36) * KDIM_ + k;
    float s = 0.f;
#pragma unroll
    for (int dd = 0; dd < 36; ++dd) s += p[(size_t)dd * KDIM_];
    s += __shfl_xor(s, 1);                        // combine 4 D-quarters
    s += __shfl_xor(s, 2);
    if (q == 0) {
        unsigned int u = __float_as_uint(s);
        u += 0x7FFFu + ((u >> 16) & 1u);          // RNE to bf16
        unsigned short hb = (unsigned short)(u >> 16);
        int kc = k >> 5, lane_ = (((k >> 3) & 3) << 4) | (o & 15);
        int hh = o >> 4, e = k & 7;
        Bpack[(((kc * 2 + hh) * 64) + lane_) * 8 + e] = hb;
    }
}

// ---------- fused basis + MFMA GEMM + BN partials from registers ----------
__global__ void __launch_bounds__(256, 2)
main_kernel(const float* __restrict__ x, const unsigned int* __restrict__ Bpack,
            float* __restrict__ out, float* __restrict__ part) {
    constexpr float A_S = 2.1019642153762871f;   // sqrt(log2 e) * 7/4

    __shared__ uint4 Bsh[KC_ * 2 * 64];          // 73728 B; reused for reduce

    const uint4* Bg = reinterpret_cast<const uint4*>(Bpack);
#pragma unroll
    for (int i = 0; i < 18; ++i) {
        int idx = threadIdx.x + i * 256;
        Bsh[idx] = Bg[idx];
    }

    int tid  = threadIdx.x;
    int l    = tid & 63;
    int wv   = tid >> 6;
    int m    = l & 15;           // output-channel base / pixel col in tile
    int hi   = l >> 4;           // k-group
    int pixbase = blockIdx.x * 64 + wv * 16;
    int n    = pixbase + m;
    int b    = n >> 12;
    int y    = (n >> 6) & 63;
    int xc   = n & 63;
    const float* xb = x + ((size_t)b << 16);

    // issue all 36 x-loads up front (independent, latency-pipelined)
    float p[KC_];
#pragma unroll
    for (int kc = 0; kc < KC_; ++kc) {
        int d  = kc * 4 + hi;
        int c  = (d * 57) >> 9;          // d/9
        int r9 = d - c * 9;
        int kh = (r9 * 11) >> 5;         // r9/3
        int kw = r9 - kh * 3;
        int iy = y + kh - 1;
        int ix = xc + kw - 1;
        bool valid = ((unsigned)iy < 64u) & ((unsigned)ix < 64u);
        p[kc] = valid ? xb[(c << 12) + (iy << 6) + ix] : 0.f;
    }
    __syncthreads();                     // B staged

    f32x4 acc0 = {0.f, 0.f, 0.f, 0.f};
    f32x4 acc1 = {0.f, 0.f, 0.f, 0.f};

#pragma unroll
    for (int kc = 0; kc < KC_; ++kc) {
        float pv = p[kc];
        float e[G_];
#pragma unroll
        for (int g = 0; g < G_; ++g) {
            float gv = -2.0f + (float)g * (4.0f / 7.0f);
            float r  = fmaf(pv, A_S, -gv * A_S);
            e[g] = __builtin_amdgcn_exp2f(-(r * r));
        }
        uint4 au;
        au.x = pack2bf(e[0], e[1]);
        au.y = pack2bf(e[2], e[3]);
        au.z = pack2bf(e[4], e[5]);
        au.w = pack2bf(e[6], e[7]);
        short8v afrag = __builtin_bit_cast(short8v, au);

        short8v b0 = __builtin_bit_cast(short8v, Bsh[(kc * 2 + 0) * 64 + l]);
        short8v b1 = __builtin_bit_cast(short8v, Bsh[(kc * 2 + 1) * 64 + l]);
        acc0 = __builtin_amdgcn_mfma_f32_16x16x32_bf16(afrag, b0, acc0, 0, 0, 0);
        acc1 = __builtin_amdgcn_mfma_f32_16x16x32_bf16(afrag, b1, acc1, 0, 0, 0);
    }

    // store raw GEMM result
    int prp = (pixbase & 4095) + hi * 4;
    float* dst0 = out + (((size_t)(b * O_ + m)) << 12) + prp;
    float* dst1 = out + (((size_t)(b * O_ + m + 16)) << 12) + prp;
    *reinterpret_cast<f32x4*>(dst0) = acc0;
    *reinterpret_cast<f32x4*>(dst1) = acc1;

    // BN partials from registers: per-block 64 floats (s[32] | q[32])
    float s0 = acc0.x + acc0.y + acc0.z + acc0.w;
    float q0 = acc0.x*acc0.x + acc0.y*acc0.y + acc0.z*acc0.z + acc0.w*acc0.w;
    float s1 = acc1.x + acc1.y + acc1.z + acc1.w;
    float q1 = acc1.x*acc1.x + acc1.y*acc1.y + acc1.z*acc1.z + acc1.w*acc1.w;
    s0 += __shfl_xor(s0, 16); s0 += __shfl_xor(s0, 32);
    q0 += __shfl_xor(q0, 16); q0 += __shfl_xor(q0, 32);
    s1 += __shfl_xor(s1, 16); s1 += __shfl_xor(s1, 32);
    q1 += __shfl_xor(q1, 16); q1 += __shfl_xor(q1, 32);

    float* red = (float*)Bsh;
    __syncthreads();                     // done reading Bsh
    if (l < 16) {
        red[wv * 64 +      m] = s0;
        red[wv * 64 + 16 + m] = s1;
        red[wv * 64 + 32 + m] = q0;
        red[wv * 64 + 48 + m] = q1;
    }
    __syncthreads();
    if (tid < 64) {
        part[blockIdx.x * 64 + tid] =
            red[tid] + red[64 + tid] + red[128 + tid] + red[192 + tid];
    }
}

// ---------- BN apply: block bid owns plane bid; o = bid&31 uniform ----------
__global__ void __launch_bounds__(256)
bn_apply(float* __restrict__ out, const float* __restrict__ part,
         const float* __restrict__ gamma, const float* __restrict__ beta) {
    __shared__ float red[256 + 64];
    int tid = threadIdx.x;
    int ch  = tid & 63, grp = tid >> 6;
    float a = 0.f;
#pragma unroll 8
    for (int i = 0; i < 128; ++i)
        a += part[(grp * 128 + i) * 64 + ch];
    red[grp * 64 + ch] = a;
    __syncthreads();
    if (tid < 64)
        red[256 + tid] = red[tid] + red[64 + tid] + red[128 + tid] + red[192 + tid];
    __syncthreads();

    int o = blockIdx.x & 31;
    float S = red[256 + o], Q = red[256 + 32 + o];
    float mean = S * (1.f / (float)NPIX_);
    float var  = Q * (1.f / (float)NPIX_) - mean * mean;
    float rstd = rsqrtf(var + 1e-5f);
    float sc   = gamma[o] * rstd;
    float sh   = beta[o] - mean * sc;

    float4* f4 = reinterpret_cast<float4*>(out) + (size_t)blockIdx.x * 1024;
#pragma unroll
    for (int j = 0; j < 4; ++j) {
        float4 v = f4[tid + j * 256];
        v.x = v.x * sc + sh; v.y = v.y * sc + sh;
        v.z = v.z * sc + sh; v.w = v.w * sc + sh;
        f4[tid + j * 256] = v;
    }
}

extern "C" void kernel_launch(void* const* d_in, const int* in_sizes, int n_in,
                              void* d_out, int out_size, void* d_ws, size_t ws_size,
                              hipStream_t stream) {
    const float* x     = (const float*)d_in[0];
    const float* W     = (const float*)d_in[1];
    const float* gamma = (const float*)d_in[2];
    const float* beta  = (const float*)d_in[3];
    float* out = (float*)d_out;
    unsigned short* Bpack = (unsigned short*)d_ws;
    float* part = (float*)((char*)d_ws + PART_OFF);

    hipLaunchKernelGGL(wsum_kernel, dim3(576), dim3(256), 0, stream, W, Bpack);
    hipLaunchKernelGGL(main_kernel, dim3(NBLK_), dim3(256), 0, stream,
                       x, (const unsigned int*)Bpack, out, part);
    hipLaunchKernelGGL(bn_apply, dim3(256), dim3(256), 0, stream,
                       out, part, gamma, beta);
}

// Round 6
// 28.275 us; speedup vs baseline: 7.2208x; 1.0533x over previous
//
#include <hip/hip_runtime.h>

#define G_     8
#define D_     144
#define O_     32
#define CIN_   16
#define BATCH_ 8
#define KDIM_  (D_*G_)            // 1152
#define NPIX_  (BATCH_*64*64)     // 32768
#define KC_    (KDIM_/32)         // 36
#define NBLK_  256                // main blocks (128 pixels each)

typedef float  f32x4   __attribute__((ext_vector_type(4)));
typedef short  short8v __attribute__((ext_vector_type(8)));
typedef unsigned short ushort4v __attribute__((ext_vector_type(4)));

// ws layout:
//   [0, 73728)         Bpack: ushort[36][2][64][8]  bf16 B-fragments
//   [73728, 90112)     part:  float[256][64]  (s[32] | q[32]) per main-block
#define PART_OFF  73728

__device__ __forceinline__ unsigned int pack2bf(float a, float b) {
    unsigned int ua = __float_as_uint(a) + 0x8000u;
    unsigned int ub = __float_as_uint(b) + 0x8000u;
    return __builtin_amdgcn_perm(ub, ua, 0x07060302u);   // {hi16(ub),hi16(ua)}
}

// ---------- Wsum -> bf16 B-fragments ----------
// 73728 threads: 8 d-splits x 9216 (o,k4) pairs; float4 loads, 128B segments.
__global__ void __launch_bounds__(256)
wsum_kernel(const float* __restrict__ W, unsigned short* __restrict__ Bpack) {
    int t  = blockIdx.x * 256 + threadIdx.x;
    int s  = t & 7;                      // d-split (lane bits 0..2)
    int pr = t >> 3;                     // (o, k4)
    int o  = pr / (KDIM_ / 4);
    int k4 = pr - o * (KDIM_ / 4);
    const float4* p = reinterpret_cast<const float4*>(
        W + (size_t)o * (D_ * KDIM_) + (size_t)(s * 18) * KDIM_) + k4;
    float4 a = make_float4(0.f, 0.f, 0.f, 0.f);
#pragma unroll
    for (int dd = 0; dd < 18; ++dd) {
        float4 v = p[dd * (KDIM_ / 4)];
        a.x += v.x; a.y += v.y; a.z += v.z; a.w += v.w;
    }
    // combine 8 d-splits across lanes
    a.x += __shfl_xor(a.x, 1); a.y += __shfl_xor(a.y, 1);
    a.z += __shfl_xor(a.z, 1); a.w += __shfl_xor(a.w, 1);
    a.x += __shfl_xor(a.x, 2); a.y += __shfl_xor(a.y, 2);
    a.z += __shfl_xor(a.z, 2); a.w += __shfl_xor(a.w, 2);
    a.x += __shfl_xor(a.x, 4); a.y += __shfl_xor(a.y, 4);
    a.z += __shfl_xor(a.z, 4); a.w += __shfl_xor(a.w, 4);
    if (s == 0) {
        float v[4] = {a.x, a.y, a.z, a.w};
        ushort4v hb;
#pragma unroll
        for (int j = 0; j < 4; ++j) {
            unsigned int u = __float_as_uint(v[j]);
            u += 0x7FFFu + ((u >> 16) & 1u);          // RNE to bf16
            hb[j] = (unsigned short)(u >> 16);
        }
        int k  = k4 * 4;
        int kc = k >> 5;
        int lane_ = (((k >> 3) & 3) << 4) | (o & 15);
        int hh = o >> 4, e = k & 7;                   // e is 0 or 4
        *reinterpret_cast<ushort4v*>(
            &Bpack[(((kc * 2 + hh) * 64) + lane_) * 8 + e]) = hb;
    }
}

// ---------- fused basis + MFMA GEMM + BN partials ----------
// 512 threads (8 waves, 128 pixels) per block; 72KB LDS -> 2 blk/CU = 4 w/SIMD
__global__ void __launch_bounds__(512, 2)
main_kernel(const float* __restrict__ x, const unsigned int* __restrict__ Bpack,
            float* __restrict__ out, float* __restrict__ part) {
    constexpr float A_S = 2.1019642153762871f;   // sqrt(log2 e) * 7/4

    __shared__ uint4 Bsh[KC_ * 2 * 64];          // 73728 B; reused for reduce

    const uint4* Bg = reinterpret_cast<const uint4*>(Bpack);
#pragma unroll
    for (int i = 0; i < 9; ++i) {
        int idx = threadIdx.x + i * 512;
        Bsh[idx] = Bg[idx];
    }

    int tid  = threadIdx.x;
    int l    = tid & 63;
    int wv   = tid >> 6;         // 0..7
    int m    = l & 15;
    int hi   = l >> 4;
    int pixbase = blockIdx.x * 128 + wv * 16;
    int n    = pixbase + m;
    int b    = n >> 12;
    int y    = (n >> 6) & 63;
    int xc   = n & 63;
    const float* xb = x + ((size_t)b << 16);

    // issue all 36 x-loads up front
    float p[KC_];
#pragma unroll
    for (int kc = 0; kc < KC_; ++kc) {
        int d  = kc * 4 + hi;
        int c  = (d * 57) >> 9;          // d/9
        int r9 = d - c * 9;
        int kh = (r9 * 11) >> 5;         // r9/3
        int kw = r9 - kh * 3;
        int iy = y + kh - 1;
        int ix = xc + kw - 1;
        bool valid = ((unsigned)iy < 64u) & ((unsigned)ix < 64u);
        p[kc] = valid ? xb[(c << 12) + (iy << 6) + ix] : 0.f;
    }
    __syncthreads();                     // B staged

    f32x4 acc0 = {0.f, 0.f, 0.f, 0.f};
    f32x4 acc1 = {0.f, 0.f, 0.f, 0.f};

#pragma unroll
    for (int kc = 0; kc < KC_; ++kc) {
        float pv = p[kc];
        float e[G_];
#pragma unroll
        for (int g = 0; g < G_; ++g) {
            float gv = -2.0f + (float)g * (4.0f / 7.0f);
            float r  = fmaf(pv, A_S, -gv * A_S);
            e[g] = __builtin_amdgcn_exp2f(-(r * r));
        }
        uint4 au;
        au.x = pack2bf(e[0], e[1]);
        au.y = pack2bf(e[2], e[3]);
        au.z = pack2bf(e[4], e[5]);
        au.w = pack2bf(e[6], e[7]);
        short8v afrag = __builtin_bit_cast(short8v, au);

        short8v b0 = __builtin_bit_cast(short8v, Bsh[(kc * 2 + 0) * 64 + l]);
        short8v b1 = __builtin_bit_cast(short8v, Bsh[(kc * 2 + 1) * 64 + l]);
        acc0 = __builtin_amdgcn_mfma_f32_16x16x32_bf16(afrag, b0, acc0, 0, 0, 0);
        acc1 = __builtin_amdgcn_mfma_f32_16x16x32_bf16(afrag, b1, acc1, 0, 0, 0);
    }

    // store raw GEMM result
    int prp = (pixbase & 4095) + hi * 4;
    float* dst0 = out + (((size_t)(b * O_ + m)) << 12) + prp;
    float* dst1 = out + (((size_t)(b * O_ + m + 16)) << 12) + prp;
    *reinterpret_cast<f32x4*>(dst0) = acc0;
    *reinterpret_cast<f32x4*>(dst1) = acc1;

    // BN partials from registers
    float s0 = acc0.x + acc0.y + acc0.z + acc0.w;
    float q0 = acc0.x*acc0.x + acc0.y*acc0.y + acc0.z*acc0.z + acc0.w*acc0.w;
    float s1 = acc1.x + acc1.y + acc1.z + acc1.w;
    float q1 = acc1.x*acc1.x + acc1.y*acc1.y + acc1.z*acc1.z + acc1.w*acc1.w;
    s0 += __shfl_xor(s0, 16); s0 += __shfl_xor(s0, 32);
    q0 += __shfl_xor(q0, 16); q0 += __shfl_xor(q0, 32);
    s1 += __shfl_xor(s1, 16); s1 += __shfl_xor(s1, 32);
    q1 += __shfl_xor(q1, 16); q1 += __shfl_xor(q1, 32);

    float* red = (float*)Bsh;
    __syncthreads();                     // done reading Bsh
    if (l < 16) {
        red[wv * 64 +      m] = s0;
        red[wv * 64 + 16 + m] = s1;
        red[wv * 64 + 32 + m] = q0;
        red[wv * 64 + 48 + m] = q1;
    }
    __syncthreads();
    if (tid < 64) {
        float v = 0.f;
#pragma unroll
        for (int w = 0; w < 8; ++w) v += red[w * 64 + tid];
        part[blockIdx.x * 64 + tid] = v;
    }
}

// ---------- BN apply: block bid owns plane bid; o = bid&31 uniform ----------
__global__ void __launch_bounds__(256)
bn_apply(float* __restrict__ out, const float* __restrict__ part,
         const float* __restrict__ gamma, const float* __restrict__ beta) {
    __shared__ float red[256 + 64];
    int tid = threadIdx.x;
    int ch  = tid & 63, grp = tid >> 6;
    float a = 0.f;
#pragma unroll 8
    for (int i = 0; i < 64; ++i)
        a += part[(grp * 64 + i) * 64 + ch];
    red[grp * 64 + ch] = a;
    __syncthreads();
    if (tid < 64)
        red[256 + tid] = red[tid] + red[64 + tid] + red[128 + tid] + red[192 + tid];
    __syncthreads();

    int o = blockIdx.x & 31;
    float S = red[256 + o], Q = red[256 + 32 + o];
    float mean = S * (1.f / (float)NPIX_);
    float var  = Q * (1.f / (float)NPIX_) - mean * mean;
    float rstd = rsqrtf(var + 1e-5f);
    float sc   = gamma[o] * rstd;
    float sh   = beta[o] - mean * sc;

    float4* f4 = reinterpret_cast<float4*>(out) + (size_t)blockIdx.x * 1024;
#pragma unroll
    for (int j = 0; j < 4; ++j) {
        float4 v = f4[tid + j * 256];
        v.x = v.x * sc + sh; v.y = v.y * sc + sh;
        v.z = v.z * sc + sh; v.w = v.w * sc + sh;
        f4[tid + j * 256] = v;
    }
}

extern "C" void kernel_launch(void* const* d_in, const int* in_sizes, int n_in,
                              void* d_out, int out_size, void* d_ws, size_t ws_size,
                              hipStream_t stream) {
    const float* x     = (const float*)d_in[0];
    const float* W     = (const float*)d_in[1];
    const float* gamma = (const float*)d_in[2];
    const float* beta  = (const float*)d_in[3];
    float* out = (float*)d_out;
    unsigned short* Bpack = (unsigned short*)d_ws;
    float* part = (float*)((char*)d_ws + PART_OFF);

    hipLaunchKernelGGL(wsum_kernel, dim3(288), dim3(256), 0, stream, W, Bpack);
    hipLaunchKernelGGL(main_kernel, dim3(NBLK_), dim3(512), 0, stream,
                       x, (const unsigned int*)Bpack, out, part);
    hipLaunchKernelGGL(bn_apply, dim3(256), dim3(256), 0, stream,
                       out, part, gamma, beta);
}